// Round 6
// baseline (323.888 us; speedup 1.0000x reference)
//
#include <hip/hip_runtime.h>

#define BLK 256
#define DD  48
#define STR 257   // odd stride: transposed LDS tile, <=2-way banking both directions

// rho = a0*I + v.sigma  (a0, v complex). Conjugation by
// U = Rz(-p1) Ry(p0) Rz(-p2) leaves a0 invariant and rotates v by the same
// SO(3) Euler product applied rightmost-first: z(-p2), y(+p0), z(-p1).
__global__ __launch_bounds__(BLK) void qlayer_kernel(
    const float* __restrict__ rho_real,
    const float* __restrict__ rho_imag,
    const float* __restrict__ x,
    const float* __restrict__ w,
    const float* __restrict__ theta,
    float* __restrict__ out,
    long long n,            // number of elements B
    long long out_floats)   // d_out capacity in floats (4*n: REAL part only)
{
    // Half-row staging: 24 floats/element, transposed. 24*257*4 = 24.7 KB
    // -> 6 blocks/CU (24 waves) vs full-row staging's 3 blocks (R3).
    __shared__ float sx[24 * STR];

    const int tid = threadIdx.x;
    const long long blockBase = (long long)blockIdx.x * BLK;
    const long long b = blockBase + tid;
    const bool active = (b < n);

    // --- Bloch decomposition (imag of a0 is dead for the real-part output) ---
    float a0r = 0.f, v1r = 0.f, v1i = 0.f, v2r = 0.f, v2i = 0.f, v3r = 0.f, v3i = 0.f;
    if (active) {
        float4 rr = reinterpret_cast<const float4*>(rho_real)[b];
        float4 ri = reinterpret_cast<const float4*>(rho_imag)[b];
        a0r = 0.5f * (rr.x + rr.w);
        v1r = 0.5f * (rr.y + rr.z);  v1i = 0.5f * (ri.y + ri.z);
        v2r = 0.5f * (ri.z - ri.y);  v2i = 0.5f * (rr.y - rr.z);
        v3r = 0.5f * (rr.x - rr.w);  v3i = 0.5f * (ri.x - ri.w);
    }

    const float4* __restrict__ x4 = reinterpret_cast<const float4*>(x);

    #pragma unroll
    for (int h = 0; h < 2; ++h) {
        // --- Stage half-rows (24 floats x 256 elements), near-coalesced ---
        // Flat float4 index f covers 96 B contiguous segments per element;
        // consecutive lanes mostly hit consecutive addresses.
        #pragma unroll
        for (int i = 0; i < 6; ++i) {
            int f = tid + BLK * i;          // 0..1535
            int e = f / 6;                  // element within block
            int q = f - 6 * e;              // float4 within half-row
            long long ge = blockBase + e;
            float4 v = make_float4(0.f, 0.f, 0.f, 0.f);
            if (ge < n) v = x4[ge * 12 + h * 6 + q];
            int jb = q * 4;                 // float index within half-row
            sx[(jb + 0) * STR + e] = v.x;
            sx[(jb + 1) * STR + e] = v.y;
            sx[(jb + 2) * STR + e] = v.z;
            sx[(jb + 3) * STR + e] = v.w;
        }
        __syncthreads();

        // --- 8 rotations consuming this half ---
        #pragma unroll
        for (int r = 0; r < 8; ++r) {
            const int J = 24 * h + 3 * r;   // compile-time -> scalar w/theta loads
            float p0 = fmaf(sx[(3 * r + 0) * STR + tid], w[J + 0], theta[J + 0]);
            float p1 = fmaf(sx[(3 * r + 1) * STR + tid], w[J + 1], theta[J + 1]);
            float p2 = fmaf(sx[(3 * r + 2) * STR + tid], w[J + 2], theta[J + 2]);

            float s0, c0, s1, c1, s2, c2;
            __sincosf(p0, &s0, &c0);
            __sincosf(p1, &s1, &c1);
            __sincosf(p2, &s2, &c2);

            // Rz(-p2) on (v1,v2)
            float n1r = fmaf(c2, v1r,  s2 * v2r);
            float n1i = fmaf(c2, v1i,  s2 * v2i);
            float n2r = fmaf(c2, v2r, -s2 * v1r);
            float n2i = fmaf(c2, v2i, -s2 * v1i);
            // Ry(p0) on (v1,v3)
            float m1r = fmaf(c0, n1r,  s0 * v3r);
            float m1i = fmaf(c0, n1i,  s0 * v3i);
            float m3r = fmaf(c0, v3r, -s0 * n1r);
            float m3i = fmaf(c0, v3i, -s0 * n1i);
            // Rz(-p1) on (v1,v2)
            v1r = fmaf(c1, m1r,  s1 * n2r);
            v1i = fmaf(c1, m1i,  s1 * n2i);
            v2r = fmaf(c1, n2r, -s1 * m1r);
            v2i = fmaf(c1, n2i, -s1 * m1i);
            v3r = m3r;
            v3i = m3i;
        }
        if (h == 0) __syncthreads();    // WAR: reads done before restaging
    }

    // --- Reassemble REAL parts only ---
    if (active) {
        if (4 * b + 4 <= out_floats) {
            reinterpret_cast<float4*>(out)[b] =
                make_float4(a0r + v3r, v1r + v2i, v1r - v2i, a0r - v3r);
        } else {
            float vals[4] = {a0r + v3r, v1r + v2i, v1r - v2i, a0r - v3r};
            for (int j = 0; j < 4; ++j) {
                long long o = 4 * b + j;
                if (o < out_floats) out[o] = vals[j];
            }
        }
    }
}

extern "C" void kernel_launch(void* const* d_in, const int* in_sizes, int n_in,
                              void* d_out, int out_size, void* d_ws, size_t ws_size,
                              hipStream_t stream) {
    const float* rho_real = (const float*)d_in[0];
    const float* rho_imag = (const float*)d_in[1];
    const float* x        = (const float*)d_in[2];
    const float* w        = (const float*)d_in[3];
    const float* theta    = (const float*)d_in[4];
    float* out = (float*)d_out;

    long long nB = (long long)in_sizes[0] / 4;
    long long nX = (long long)in_sizes[2] / DD;
    long long n  = nB < nX ? nB : nX;
    if (n <= 0) return;

    int grid = (int)((n + BLK - 1) / BLK);
    qlayer_kernel<<<dim3(grid), dim3(BLK), 0, stream>>>(
        rho_real, rho_imag, x, w, theta, out, n, (long long)out_size);
}

// Round 7
// 308.090 us; speedup vs baseline: 1.0513x; 1.0513x over previous
//
#include <hip/hip_runtime.h>

#define BLK 256
#define DD  48
#define INV2PI 0.15915494309189535f   // v_sin/v_cos take revolutions

// rho = a0*I + v.sigma (a0, v complex). Conjugation by U_k = Rz(-p1k)Ry(p0k)Rz(-p2k)
// leaves a0 invariant and rotates v. Adjacent Rz's across blocks merge:
//   Z(-p2_0), then for k=0..14: Y(p0_k), Z(-(p1_k + p2_{k+1})), then Y(p0_15), Z(-p1_15)
// => 33 rotations / 33 native sincos instead of 48.
__global__ __launch_bounds__(BLK) void qlayer_kernel(
    const float* __restrict__ rho_real,
    const float* __restrict__ rho_imag,
    const float* __restrict__ x,
    const float* __restrict__ w,
    const float* __restrict__ theta,
    float* __restrict__ out,
    long long n,            // number of elements B
    long long out_floats)   // d_out capacity in floats (4*n: REAL part only)
{
    const long long b = (long long)blockIdx.x * BLK + threadIdx.x;
    if (b >= n) return;

    // --- Load rho (coalesced float4) + Bloch decomposition ---
    float4 rr = reinterpret_cast<const float4*>(rho_real)[b];
    float4 ri = reinterpret_cast<const float4*>(rho_imag)[b];
    float a0r = 0.5f * (rr.x + rr.w);
    float v1r = 0.5f * (rr.y + rr.z), v1i = 0.5f * (ri.y + ri.z);
    float v2r = 0.5f * (ri.z - ri.y), v2i = 0.5f * (rr.y - rr.z);
    float v3r = 0.5f * (rr.x - rr.w), v3i = 0.5f * (ri.x - ri.w);

    // --- Load this element's x row: 12 float4s, 192 B ---
    const float4* __restrict__ xv = reinterpret_cast<const float4*>(x + b * DD);
    float xs[DD];
    #pragma unroll
    for (int q = 0; q < 12; ++q) {
        float4 v = xv[q];
        xs[4 * q + 0] = v.x; xs[4 * q + 1] = v.y;
        xs[4 * q + 2] = v.z; xs[4 * q + 3] = v.w;
    }

    // Plane-rotation helpers (native HW trig). Angle semantics match the
    // verified R5 kernel: rotZ(a) == Rz(-a) on (v1,v2); rotY(a) == Ry(a) on (v1,v3).
    auto rotZ = [&](float ang) {
        float s = __builtin_amdgcn_sinf(ang * INV2PI);
        float c = __builtin_amdgcn_cosf(ang * INV2PI);
        float t1r = fmaf(c, v1r,  s * v2r);
        float t1i = fmaf(c, v1i,  s * v2i);
        v2r = fmaf(c, v2r, -s * v1r);
        v2i = fmaf(c, v2i, -s * v1i);
        v1r = t1r; v1i = t1i;
    };
    auto rotY = [&](float ang) {
        float s = __builtin_amdgcn_sinf(ang * INV2PI);
        float c = __builtin_amdgcn_cosf(ang * INV2PI);
        float t1r = fmaf(c, v1r,  s * v3r);
        float t1i = fmaf(c, v1i,  s * v3i);
        v3r = fmaf(c, v3r, -s * v1r);
        v3i = fmaf(c, v3i, -s * v1i);
        v1r = t1r; v1i = t1i;
    };

    // --- Merged rotation chain ---
    rotZ(fmaf(xs[2], w[2], theta[2]));                       // Z(-p2_0)
    #pragma unroll
    for (int k = 0; k < 15; ++k) {
        const int j = 3 * k;
        rotY(fmaf(xs[j], w[j], theta[j]));                   // Y(p0_k)
        // Z(-(p1_k + p2_{k+1})): theta-sum is scalar math (compile-time idx)
        float ts = theta[j + 1] + theta[j + 5];
        rotZ(fmaf(xs[j + 1], w[j + 1], fmaf(xs[j + 5], w[j + 5], ts)));
    }
    rotY(fmaf(xs[45], w[45], theta[45]));                    // Y(p0_15)
    rotZ(fmaf(xs[46], w[46], theta[46]));                    // Z(-p1_15)

    // --- Reassemble REAL parts only ---
    if (4 * b + 4 <= out_floats) {
        reinterpret_cast<float4*>(out)[b] =
            make_float4(a0r + v3r, v1r + v2i, v1r - v2i, a0r - v3r);
    } else {
        float vals[4] = {a0r + v3r, v1r + v2i, v1r - v2i, a0r - v3r};
        for (int j = 0; j < 4; ++j) {
            long long o = 4 * b + j;
            if (o < out_floats) out[o] = vals[j];
        }
    }
}

extern "C" void kernel_launch(void* const* d_in, const int* in_sizes, int n_in,
                              void* d_out, int out_size, void* d_ws, size_t ws_size,
                              hipStream_t stream) {
    const float* rho_real = (const float*)d_in[0];
    const float* rho_imag = (const float*)d_in[1];
    const float* x        = (const float*)d_in[2];
    const float* w        = (const float*)d_in[3];
    const float* theta    = (const float*)d_in[4];
    float* out = (float*)d_out;

    long long nB = (long long)in_sizes[0] / 4;
    long long nX = (long long)in_sizes[2] / DD;
    long long n  = nB < nX ? nB : nX;
    if (n <= 0) return;

    int grid = (int)((n + BLK - 1) / BLK);
    qlayer_kernel<<<dim3(grid), dim3(BLK), 0, stream>>>(
        rho_real, rho_imag, x, w, theta, out, n, (long long)out_size);
}